// Round 8
// baseline (1838.273 us; speedup 1.0000x reference)
//
#include <hip/hip_runtime.h>
#include <cstdint>
#include <cstddef>

typedef short short8_t __attribute__((ext_vector_type(8)));
typedef float float4_t __attribute__((ext_vector_type(4)));

// Fragment-packed weights (rebuilt from d_in every call).
// g_W frag f = ((g*4+w4)*4+s)*12 + kt  (cols g*256 + w4*64 + s*16, k-tile kt; k 0..127 Wih, 128..383 Whh)
__device__ __align__(16) unsigned short g_W[1024 * 384];
// g_Weff frag f = ((g*4+w4)*4+s)*8 + kt2 ; Weff = Whh + Wih @ wlin  (AR recurrence fold)
__device__ __align__(16) unsigned short g_Weff[1024 * 256];
__device__ __align__(16) unsigned short g_Wlin[128 * 256];
__device__ float g_bias[1024];   // b_ih + b_hh
__device__ float g_beff[1024];   // bias + Wih @ b_lin
__device__ float g_blin[128];

__device__ __forceinline__ unsigned short f2bf_rn(float f) {
    union { float f; unsigned int u; } v; v.f = f;
    unsigned int u = v.u;
    return (unsigned short)((u + 0x7FFFu + ((u >> 16) & 1u)) >> 16);
}
__device__ __forceinline__ float sigm(float x) { return 1.0f / (1.0f + __expf(-x)); }
__device__ __forceinline__ float tanh_fast(float x) { return 2.0f / (1.0f + __expf(-2.0f * x)) - 1.0f; }

__global__ void prep_kernel(const float* __restrict__ w_ih, const float* __restrict__ w_hh,
                            const float* __restrict__ b_ih, const float* __restrict__ b_hh,
                            const float* __restrict__ w_lin, const float* __restrict__ b_lin) {
    int idx = blockIdx.x * blockDim.x + threadIdx.x;
    int stride = gridDim.x * blockDim.x;
    for (int i = idx; i < 49152; i += stride) {   // 768 frags * 64 lanes
        int f = i >> 6, l = i & 63;
        int kt = f % 12, rest = f / 12;
        int s = rest & 3, wvv = (rest >> 2) & 3, g = rest >> 4;
        int n = g * 256 + wvv * 64 + s * 16 + (l & 15);
        int k0 = kt * 32 + (l >> 4) * 8;
        unsigned short* dst = g_W + f * 512 + l * 8;
#pragma unroll
        for (int j = 0; j < 8; ++j) {
            int k = k0 + j;
            float v = (k < 128) ? w_ih[n * 128 + k] : w_hh[n * 256 + (k - 128)];
            dst[j] = f2bf_rn(v);
        }
    }
    for (int i = idx; i < 4096; i += stride) {    // wlin: 64 frags * 64 lanes
        int f = i >> 6, l = i & 63;
        int kt = f & 7, wss = f >> 3;
        int s = wss & 1, wvv = wss >> 1;
        int n = wvv * 32 + s * 16 + (l & 15);
        int k0 = kt * 32 + (l >> 4) * 8;
        unsigned short* dst = g_Wlin + f * 512 + l * 8;
#pragma unroll
        for (int j = 0; j < 8; ++j)
            dst[j] = f2bf_rn(w_lin[n * 256 + k0 + j]);
    }
    for (int i = idx; i < 1024; i += stride) g_bias[i] = b_ih[i] + b_hh[i];
    for (int i = idx; i < 128; i += stride) g_blin[i] = b_lin[i];
}

// Weff[n][k] = Whh[n][k] + sum_p Wih[n][p]*wlin[p][k]; beff = bias + Wih@blin
__global__ void prep2_kernel(const float* __restrict__ w_ih, const float* __restrict__ w_hh,
                             const float* __restrict__ w_lin, const float* __restrict__ b_ih,
                             const float* __restrict__ b_hh, const float* __restrict__ b_lin) {
    int i = blockIdx.x * 256 + threadIdx.x;       // grid 1024*256 = 262144
    {
        int e = i & 511, f = i >> 9;
        int l = e >> 3, j = e & 7;
        int kt2 = f & 7, rest = f >> 3;
        int s = rest & 3, w = (rest >> 2) & 3, g = rest >> 4;
        int n = g * 256 + w * 64 + s * 16 + (l & 15);
        int k = kt2 * 32 + (l >> 4) * 8 + j;
        float acc = w_hh[n * 256 + k];
#pragma unroll 4
        for (int p = 0; p < 128; ++p)
            acc += w_ih[n * 128 + p] * w_lin[p * 256 + k];
        g_Weff[f * 512 + e] = f2bf_rn(acc);
    }
    if (i < 1024) {
        float acc = b_ih[i] + b_hh[i];
        for (int p = 0; p < 128; ++p)
            acc += w_ih[i * 128 + p] * b_lin[p];
        g_beff[i] = acc;
    }
}

// One block = 1024 threads = 16 waves owns 16 batch rows for all 95 steps.
// Wave w holds gate cols {g*256 + w*16 .. +16} (all 4 gates) permanently in
// 192 VGPRs of B-fragments; h broadcast wave<->wave via 2x16KB swizzled LDS,
// ONE __syncthreads per step. Zero cross-block communication.
__global__ void __launch_bounds__(1024, 1) lstm_persist(const float* __restrict__ inp,
                                                        float* __restrict__ out) {
    __shared__ __align__(16) unsigned short h_lds[2][16 * 256];

    const int tid = threadIdx.x;
    const int w = tid >> 6, l = tid & 63, l15 = l & 15, lg = l >> 4;
    const int blk = blockIdx.x;          // 128 blocks, rows [blk*16, blk*16+16)

    // ---- persistent weights: 48 enc B-frags -> 192 VGPRs ----
    short8_t wreg[48];
#pragma unroll
    for (int g = 0; g < 4; ++g)
#pragma unroll
        for (int kt = 0; kt < 12; ++kt) {
            int f = g * 192 + (w >> 2) * 48 + (w & 3) * 12 + kt;   // cols g*256 + w*16
            wreg[g * 12 + kt] = *(const short8_t*)&g_W[f * 512 + l * 8];
        }
    short8_t wlreg[8];
    if (w < 8) {
#pragma unroll
        for (int kt = 0; kt < 8; ++kt)                              // pred cols w*16..+16
            wlreg[kt] = *(const short8_t*)&g_Wlin[(w * 8 + kt) * 512 + l * 8];
    }
    float biasr[4], beffr[4];
#pragma unroll
    for (int g = 0; g < 4; ++g) {
        biasr[g] = g_bias[g * 256 + w * 16 + l15];
        beffr[g] = g_beff[g * 256 + w * 16 + l15];
    }
    const float blin_r = (w < 8) ? g_blin[w * 16 + l15] : 0.0f;

    float c_st[4] = {0.0f, 0.0f, 0.0f, 0.0f};
    short8_t ha[8], xa[4];
    float4_t xf[8];

    const float* xrow = inp + (size_t)(blk * 16 + l15) * 8192 + lg * 8;
    // prologue: load + convert x(0)
#pragma unroll
    for (int kt = 0; kt < 4; ++kt) {
        xf[2 * kt]     = *(const float4_t*)(xrow + kt * 32);
        xf[2 * kt + 1] = *(const float4_t*)(xrow + kt * 32 + 4);
    }
#pragma unroll
    for (int kt = 0; kt < 4; ++kt) {
        short8_t vv;
        vv[0] = (short)f2bf_rn(xf[2 * kt][0]); vv[1] = (short)f2bf_rn(xf[2 * kt][1]);
        vv[2] = (short)f2bf_rn(xf[2 * kt][2]); vv[3] = (short)f2bf_rn(xf[2 * kt][3]);
        vv[4] = (short)f2bf_rn(xf[2 * kt + 1][0]); vv[5] = (short)f2bf_rn(xf[2 * kt + 1][1]);
        vv[6] = (short)f2bf_rn(xf[2 * kt + 1][2]); vv[7] = (short)f2bf_rn(xf[2 * kt + 1][3]);
        xa[kt] = vv;
    }

    // ================= encoder: t = 0..63 =================
    for (int t = 0; t < 64; ++t) {
        // issue x(t+1) loads early (full-step flight; converted at step end)
        if (t < 63) {
            const float* xp = xrow + (t + 1) * 128;
#pragma unroll
            for (int kt = 0; kt < 4; ++kt) {
                xf[2 * kt]     = *(const float4_t*)(xp + kt * 32);
                xf[2 * kt + 1] = *(const float4_t*)(xp + kt * 32 + 4);
            }
        }

        float4_t acc[4];
#pragma unroll
        for (int g = 0; g < 4; ++g)
            acc[g] = (float4_t){biasr[g], biasr[g], biasr[g], biasr[g]};

        // x-part
#pragma unroll
        for (int kt = 0; kt < 4; ++kt)
#pragma unroll
            for (int g = 0; g < 4; ++g)
                acc[g] = __builtin_amdgcn_mfma_f32_16x16x32_bf16(xa[kt], wreg[g * 12 + kt], acc[g], 0, 0, 0);

        // h-part
        if (t > 0) {
            const char* hb = (const char*)&h_lds[(t - 1) & 1][0];
#pragma unroll
            for (int kt = 0; kt < 8; ++kt) {
                int off = (l15 * 512 + kt * 64 + lg * 16) ^ ((l15 & 7) << 4);
                ha[kt] = *(const short8_t*)(hb + off);
            }
#pragma unroll
            for (int kt = 0; kt < 8; ++kt)
#pragma unroll
                for (int g = 0; g < 4; ++g)
                    acc[g] = __builtin_amdgcn_mfma_f32_16x16x32_bf16(ha[kt], wreg[g * 12 + 4 + kt], acc[g], 0, 0, 0);
        }

        // pointwise -> write h(t) slice to LDS (swizzled)
        char* hwb = (char*)&h_lds[t & 1][0];
#pragma unroll
        for (int r = 0; r < 4; ++r) {
            float ip = acc[0][r], fp = acc[1][r], gp = acc[2][r], op = acc[3][r];
            float cn = sigm(fp) * c_st[r] + sigm(ip) * tanh_fast(gp);
            c_st[r] = cn;
            float hv = sigm(op) * tanh_fast(cn);
            int row = lg * 4 + r, col = w * 16 + l15;
            int off = (row * 512 + col * 2) ^ ((row & 7) << 4);
            *(unsigned short*)(hwb + off) = f2bf_rn(hv);
        }

        // convert x(t+1) for next step
        if (t < 63) {
#pragma unroll
            for (int kt = 0; kt < 4; ++kt) {
                short8_t vv;
                vv[0] = (short)f2bf_rn(xf[2 * kt][0]); vv[1] = (short)f2bf_rn(xf[2 * kt][1]);
                vv[2] = (short)f2bf_rn(xf[2 * kt][2]); vv[3] = (short)f2bf_rn(xf[2 * kt][3]);
                vv[4] = (short)f2bf_rn(xf[2 * kt + 1][0]); vv[5] = (short)f2bf_rn(xf[2 * kt + 1][1]);
                vv[6] = (short)f2bf_rn(xf[2 * kt + 1][2]); vv[7] = (short)f2bf_rn(xf[2 * kt + 1][3]);
                xa[kt] = vv;
            }
        }
        __syncthreads();
    }

    // ---- one-time: overwrite wreg[0..31] with Weff B-frags ----
#pragma unroll
    for (int g = 0; g < 4; ++g)
#pragma unroll
        for (int kt = 0; kt < 8; ++kt) {
            int f = g * 128 + (w >> 2) * 32 + (w & 3) * 8 + kt;
            wreg[g * 8 + kt] = *(const short8_t*)&g_Weff[f * 512 + l * 8];
        }

    // ================= AR: t = 64..95 =================
    for (int t = 64; t <= 95; ++t) {
        const char* hb = (const char*)&h_lds[(t - 1) & 1][0];
#pragma unroll
        for (int kt = 0; kt < 8; ++kt) {
            int off = (l15 * 512 + kt * 64 + lg * 16) ^ ((l15 & 7) << 4);
            ha[kt] = *(const short8_t*)(hb + off);
        }

        if (t < 95) {
            float4_t acc[4];
#pragma unroll
            for (int g = 0; g < 4; ++g)
                acc[g] = (float4_t){beffr[g], beffr[g], beffr[g], beffr[g]};
#pragma unroll
            for (int kt = 0; kt < 8; ++kt)
#pragma unroll
                for (int g = 0; g < 4; ++g)
                    acc[g] = __builtin_amdgcn_mfma_f32_16x16x32_bf16(ha[kt], wreg[g * 8 + kt], acc[g], 0, 0, 0);

            char* hwb = (char*)&h_lds[t & 1][0];
#pragma unroll
            for (int r = 0; r < 4; ++r) {
                float ip = acc[0][r], fp = acc[1][r], gp = acc[2][r], op = acc[3][r];
                float cn = sigm(fp) * c_st[r] + sigm(ip) * tanh_fast(gp);
                c_st[r] = cn;
                float hv = sigm(op) * tanh_fast(cn);
                int row = lg * 4 + r, col = w * 16 + l15;
                int off = (row * 512 + col * 2) ^ ((row & 7) << 4);
                *(unsigned short*)(hwb + off) = f2bf_rn(hv);
            }
        }

        // pred(t-1) = h(t-1) @ wlin^T + blin  (waves 0..7, 16 cols each)
        if (w < 8) {
            float4_t pacc = {blin_r, blin_r, blin_r, blin_r};
#pragma unroll
            for (int kt = 0; kt < 8; ++kt)
                pacc = __builtin_amdgcn_mfma_f32_16x16x32_bf16(ha[kt], wlreg[kt], pacc, 0, 0, 0);
            int ko = t - 64;
            float* orow = out + ((size_t)(blk * 16 + lg * 4) * 32 + ko) * 128 + w * 16 + l15;
#pragma unroll
            for (int r = 0; r < 4; ++r)
                orow[(size_t)r * 32 * 128] = pacc[r];
        }

        if (t < 95) __syncthreads();
    }
}

extern "C" void kernel_launch(void* const* d_in, const int* in_sizes, int n_in,
                              void* d_out, int out_size, void* d_ws, size_t ws_size,
                              hipStream_t stream) {
    const float* inp   = (const float*)d_in[0];
    const float* w_ih  = (const float*)d_in[1];
    const float* w_hh  = (const float*)d_in[2];
    const float* b_ih  = (const float*)d_in[3];
    const float* b_hh  = (const float*)d_in[4];
    const float* w_lin = (const float*)d_in[5];
    const float* b_lin = (const float*)d_in[6];
    (void)in_sizes; (void)n_in; (void)d_ws; (void)ws_size; (void)out_size;

    prep_kernel<<<128, 256, 0, stream>>>(w_ih, w_hh, b_ih, b_hh, w_lin, b_lin);
    prep2_kernel<<<1024, 256, 0, stream>>>(w_ih, w_hh, w_lin, b_ih, b_hh, b_lin);
    lstm_persist<<<128, 1024, 0, stream>>>(inp, (float*)d_out);
}

// Round 9
// 1428.228 us; speedup vs baseline: 1.2871x; 1.2871x over previous
//
#include <hip/hip_runtime.h>
#include <cstdint>
#include <cstddef>

typedef short short8_t __attribute__((ext_vector_type(8)));
typedef float float4_t __attribute__((ext_vector_type(4)));
typedef unsigned int uint4_t __attribute__((ext_vector_type(4)));

#define REGF 92   // Whh frags per wave in VGPRs
#define LDSF 36   // Whh frags per wave in LDS  (REGF+LDSF = 128 = 16 coltiles x 8 ktiles)

// ---- packed weights / intermediates (rebuilt every call) ----
__device__ __align__(16) unsigned short g_Whhp[4 * 128 * 512];  // [w][fw=(g*4+s)*8+kt][l*8+j]
__device__ __align__(16) unsigned short g_Weffp[4 * 128 * 512]; // same layout, Weff = Whh + Wih@wlin
__device__ __align__(16) unsigned short g_Wihp[4 * 64 * 512];   // [w][fw2=(g*4+s)*4+kt][..]
__device__ __align__(16) unsigned short g_Wlinp[4 * 16 * 512];  // [w][s2*8+kt][..]
__device__ float g_bias[1024];   // b_ih + b_hh (folded into Gx)
__device__ float g_beff[1024];   // bias + Wih @ b_lin (AR fold)
__device__ float g_blin[128];
// Gx = x @ Wih^T + bias, bf16, per (blk,t,w,lane) 128 B slabs matching acc-init order
__device__ unsigned short g_Gx[134217728];   // 128*64*4*64*64 = 256 MB

__device__ __forceinline__ unsigned short f2bf_rn(float f) {
    union { float f; unsigned int u; } v; v.f = f;
    unsigned int u = v.u;
    return (unsigned short)((u + 0x7FFFu + ((u >> 16) & 1u)) >> 16);
}
__device__ __forceinline__ float sigm(float x) { return 1.0f / (1.0f + __expf(-x)); }
__device__ __forceinline__ float tanh_fast(float x) { return 2.0f / (1.0f + __expf(-2.0f * x)) - 1.0f; }

// ---- pack Whh / Wih / wlin into fragment-major layouts + biases ----
__global__ void prep_kernel(const float* __restrict__ w_ih, const float* __restrict__ w_hh,
                            const float* __restrict__ b_ih, const float* __restrict__ b_hh,
                            const float* __restrict__ w_lin, const float* __restrict__ b_lin) {
    int idx = blockIdx.x * blockDim.x + threadIdx.x;
    int stride = gridDim.x * blockDim.x;
    for (int i = idx; i < 262144; i += stride) {           // Whh: n 0..1023, k 0..255
        int n = i >> 8, k = i & 255;
        int w = (n >> 6) & 3, g = n >> 8, s = (n >> 4) & 3, l15 = n & 15;
        int kt = k >> 5, lg = (k >> 3) & 3, j = k & 7;
        int fw = (g * 4 + s) * 8 + kt;
        g_Whhp[((size_t)(w * 128 + fw)) * 512 + (lg * 16 + l15) * 8 + j] = f2bf_rn(w_hh[n * 256 + k]);
    }
    for (int i = idx; i < 131072; i += stride) {           // Wih: n 0..1023, k 0..127
        int n = i >> 7, k = i & 127;
        int w = (n >> 6) & 3, g = n >> 8, s = (n >> 4) & 3, l15 = n & 15;
        int kt = k >> 5, lg = (k >> 3) & 3, j = k & 7;
        int fw2 = (g * 4 + s) * 4 + kt;
        g_Wihp[((size_t)(w * 64 + fw2)) * 512 + (lg * 16 + l15) * 8 + j] = f2bf_rn(w_ih[n * 128 + k]);
    }
    for (int i = idx; i < 32768; i += stride) {            // wlin: p 0..127, k 0..255
        int p = i >> 8, k = i & 255;
        int w = p >> 5, s2 = (p >> 4) & 1, l15 = p & 15;
        int kt = k >> 5, lg = (k >> 3) & 3, j = k & 7;
        g_Wlinp[((size_t)(w * 16 + s2 * 8 + kt)) * 512 + (lg * 16 + l15) * 8 + j] = f2bf_rn(w_lin[p * 256 + k]);
    }
    for (int i = idx; i < 1024; i += stride) g_bias[i] = b_ih[i] + b_hh[i];
    for (int i = idx; i < 128; i += stride) g_blin[i] = b_lin[i];
}

// Weff[n][k] = Whh[n][k] + sum_p Wih[n][p]*wlin[p][k]; beff = bias + Wih@blin
__global__ void prep2_kernel(const float* __restrict__ w_ih, const float* __restrict__ w_hh,
                             const float* __restrict__ w_lin, const float* __restrict__ b_ih,
                             const float* __restrict__ b_hh, const float* __restrict__ b_lin) {
    int i = blockIdx.x * 256 + threadIdx.x;                // grid 1024*256 = 262144
    {
        int n = i >> 8, k = i & 255;
        float acc = w_hh[n * 256 + k];
#pragma unroll 4
        for (int p = 0; p < 128; ++p)
            acc += w_ih[n * 128 + p] * w_lin[p * 256 + k];
        int w = (n >> 6) & 3, g = n >> 8, s = (n >> 4) & 3, l15 = n & 15;
        int kt = k >> 5, lg = (k >> 3) & 3, j = k & 7;
        int fw = (g * 4 + s) * 8 + kt;
        g_Weffp[((size_t)(w * 128 + fw)) * 512 + (lg * 16 + l15) * 8 + j] = f2bf_rn(acc);
    }
    if (i < 1024) {
        float acc = b_ih[i] + b_hh[i];
        for (int p = 0; p < 128; ++p)
            acc += w_ih[i * 128 + p] * b_lin[p];
        g_beff[i] = acc;
    }
}

// ---- Gx = x @ Wih^T + bias, written in the recurrent kernel's acc-init order ----
__global__ void __launch_bounds__(256, 1) gx_kernel(const float* __restrict__ inp) {
    const int b = blockIdx.x;            // 1024 = 128 blk x 8 tchunks
    const int blk = b >> 3, t0 = (b & 7) << 3;
    const int tid = threadIdx.x;
    const int w = tid >> 6, l = tid & 63, l15 = l & 15, lg = l >> 4;

    short8_t wih[64];
#pragma unroll
    for (int fi = 0; fi < 64; ++fi)
        wih[fi] = *(const short8_t*)&g_Wihp[((size_t)(w * 64 + fi)) * 512 + l * 8];
#pragma unroll
    for (int fi = 0; fi < 64; ++fi) asm volatile("" :: "v"(wih[fi]));

    float biasr[4][4];
#pragma unroll
    for (int g = 0; g < 4; ++g)
#pragma unroll
        for (int s = 0; s < 4; ++s)
            biasr[g][s] = g_bias[g * 256 + w * 64 + s * 16 + l15];

    for (int tt = 0; tt < 8; ++tt) {
        int t = t0 + tt;
        const float* xp = inp + (size_t)(blk * 16 + l15) * 8192 + t * 128 + lg * 8;
        short8_t xa[4];
#pragma unroll
        for (int kt = 0; kt < 4; ++kt) {
            float4_t a = *(const float4_t*)(xp + kt * 32);
            float4_t b2 = *(const float4_t*)(xp + kt * 32 + 4);
            short8_t vv;
            vv[0] = (short)f2bf_rn(a[0]); vv[1] = (short)f2bf_rn(a[1]);
            vv[2] = (short)f2bf_rn(a[2]); vv[3] = (short)f2bf_rn(a[3]);
            vv[4] = (short)f2bf_rn(b2[0]); vv[5] = (short)f2bf_rn(b2[1]);
            vv[6] = (short)f2bf_rn(b2[2]); vv[7] = (short)f2bf_rn(b2[3]);
            xa[kt] = vv;
        }
        float4_t acc[4][4];
#pragma unroll
        for (int g = 0; g < 4; ++g)
#pragma unroll
            for (int s = 0; s < 4; ++s) {
                float bb = biasr[g][s];
                acc[g][s] = (float4_t){bb, bb, bb, bb};
            }
#pragma unroll
        for (int kt = 0; kt < 4; ++kt)
#pragma unroll
            for (int g = 0; g < 4; ++g)
#pragma unroll
                for (int s = 0; s < 4; ++s)
                    acc[g][s] = __builtin_amdgcn_mfma_f32_16x16x32_bf16(xa[kt], wih[(g * 4 + s) * 4 + kt], acc[g][s], 0, 0, 0);

        uint4_t ov[8];
#pragma unroll
        for (int g = 0; g < 4; ++g)
#pragma unroll
            for (int s = 0; s < 4; ++s) {
                unsigned int d0 = ((unsigned)f2bf_rn(acc[g][s][1]) << 16) | f2bf_rn(acc[g][s][0]);
                unsigned int d1 = ((unsigned)f2bf_rn(acc[g][s][3]) << 16) | f2bf_rn(acc[g][s][2]);
                int e = g * 8 + s * 2;
                ov[e >> 2][e & 3] = d0;
                ov[(e + 1) >> 2][(e + 1) & 3] = d1;
            }
        char* dst = (char*)g_Gx + ((((size_t)blk * 64 + t) * 4 + w) * 64 + l) * 128;
#pragma unroll
        for (int q = 0; q < 8; ++q) *(uint4_t*)(dst + q * 16) = ov[q];
    }
}

// weight-frag accessor: compile-time reg/LDS split
#define GFRAG(FW) ((FW) < REGF ? wreg[(FW)] \
    : *(const short8_t*)&lds_w[((size_t)w * LDSF + (FW) - REGF) * 512 + l * 8])

#define GATEPASS(ACC, G) do { \
    _Pragma("unroll") \
    for (int kt = 0; kt < 8; ++kt) \
        _Pragma("unroll") \
        for (int s = 0; s < 4; ++s) \
            ACC[s] = __builtin_amdgcn_mfma_f32_16x16x32_bf16(ha[kt], GFRAG(((G)*4+s)*8+kt), ACC[s], 0, 0, 0); \
} while (0)

#define GXINIT(ACC, G) do { \
    _Pragma("unroll") \
    for (int s = 0; s < 4; ++s) { \
        unsigned int d0 = gxv[(G)*2 + (s >> 1)][(s & 1) * 2]; \
        unsigned int d1 = gxv[(G)*2 + (s >> 1)][(s & 1) * 2 + 1]; \
        ACC[s][0] = __uint_as_float(d0 << 16); \
        ACC[s][1] = __uint_as_float(d0 & 0xFFFF0000u); \
        ACC[s][2] = __uint_as_float(d1 << 16); \
        ACC[s][3] = __uint_as_float(d1 & 0xFFFF0000u); \
    } \
} while (0)

#define BINIT(ACC, G) do { \
    _Pragma("unroll") \
    for (int s = 0; s < 4; ++s) { \
        float bb = beffr[G][s]; \
        ACC[s] = (float4_t){bb, bb, bb, bb}; \
    } \
} while (0)

// 128 blocks x 256 thr (4 waves, 1 wave/SIMD, 512 VGPR). Block owns 16 rows.
// Whh resident: 92 frags/wave VGPR + 36 frags/wave LDS. h via 8KB LDS, 2 barriers/step.
__global__ void __launch_bounds__(256, 1) lstm_persist(float* __restrict__ out) {
    __shared__ __align__(16) unsigned short lds_w[4 * LDSF * 512];   // 144 KB
    __shared__ __align__(16) unsigned short h_lds[16 * 256];         // 8 KB

    const int tid = threadIdx.x;
    const int w = tid >> 6, l = tid & 63, l15 = l & 15, lg = l >> 4;
    const int blk = blockIdx.x;

    // stage LDS weight frags (Whh)
    for (int i = tid; i < 4 * LDSF * 64; i += 256) {
        int fq = i >> 6, ch = i & 63;
        int wv = fq / LDSF, q = fq % LDSF;
        *(uint4_t*)&lds_w[(size_t)fq * 512 + ch * 8] =
            *(const uint4_t*)&g_Whhp[((size_t)(wv * 128 + REGF + q)) * 512 + ch * 8];
    }
    // VGPR weight frags
    short8_t wreg[REGF];
#pragma unroll
    for (int fi = 0; fi < REGF; ++fi)
        wreg[fi] = *(const short8_t*)&g_Whhp[((size_t)(w * 128 + fi)) * 512 + l * 8];
#pragma unroll
    for (int fi = 0; fi < REGF; ++fi) asm volatile("" :: "v"(wreg[fi]));

    // Gx prefetch for t=0
    uint4_t gxv[8];
    {
        const char* gxb = (const char*)g_Gx + (((size_t)blk * 64 * 4 + w) * 64 + l) * 128;
#pragma unroll
        for (int q = 0; q < 8; ++q) gxv[q] = *(const uint4_t*)(gxb + q * 16);
    }
    float c_st[4][4];
#pragma unroll
    for (int s = 0; s < 4; ++s)
#pragma unroll
        for (int r = 0; r < 4; ++r) c_st[s][r] = 0.0f;

    short8_t ha[8];
    __syncthreads();

    // ================= encoder t = 0..63 =================
    for (int t = 0; t < 64; ++t) {
        if (t > 0) {
#pragma unroll
            for (int kt = 0; kt < 8; ++kt) {
                int off = (l15 * 512 + kt * 64 + lg * 16) ^ ((l15 & 7) << 4);
                ha[kt] = *(const short8_t*)((const char*)h_lds + off);
            }
        }
        __syncthreads();   // readers done before writers

        float4_t ai[4], af[4];
        GXINIT(ai, 0); GXINIT(af, 1);
        if (t > 0) { GATEPASS(ai, 0); GATEPASS(af, 1); }
        float4_t ag[4];
        GXINIT(ag, 2);
        if (t > 0) GATEPASS(ag, 2);
#pragma unroll
        for (int s = 0; s < 4; ++s)
#pragma unroll
            for (int r = 0; r < 4; ++r)
                c_st[s][r] = sigm(af[s][r]) * c_st[s][r] + sigm(ai[s][r]) * tanh_fast(ag[s][r]);
        float4_t ao[4];
        GXINIT(ao, 3);
        if (t < 63) {   // prefetch Gx(t+1); flight hides under o-pass + pointwise
            const char* gxb = (const char*)g_Gx + ((((size_t)blk * 64 + t + 1) * 4 + w) * 64 + l) * 128;
#pragma unroll
            for (int q = 0; q < 8; ++q) gxv[q] = *(const uint4_t*)(gxb + q * 16);
        }
        if (t > 0) GATEPASS(ao, 3);
#pragma unroll
        for (int s = 0; s < 4; ++s)
#pragma unroll
            for (int r = 0; r < 4; ++r) {
                float hv = sigm(ao[s][r]) * tanh_fast(c_st[s][r]);
                int row = lg * 4 + r, col = w * 64 + s * 16 + l15;
                int off = (row * 512 + col * 2) ^ ((row & 7) << 4);
                *(unsigned short*)((char*)h_lds + off) = f2bf_rn(hv);
            }
        __syncthreads();   // h(t) visible
    }

    // ---- swap to Weff ----
    for (int i = tid; i < 4 * LDSF * 64; i += 256) {
        int fq = i >> 6, ch = i & 63;
        int wv = fq / LDSF, q = fq % LDSF;
        *(uint4_t*)&lds_w[(size_t)fq * 512 + ch * 8] =
            *(const uint4_t*)&g_Weffp[((size_t)(wv * 128 + REGF + q)) * 512 + ch * 8];
    }
#pragma unroll
    for (int fi = 0; fi < REGF; ++fi)
        wreg[fi] = *(const short8_t*)&g_Weffp[((size_t)(w * 128 + fi)) * 512 + l * 8];
#pragma unroll
    for (int fi = 0; fi < REGF; ++fi) asm volatile("" :: "v"(wreg[fi]));
    float beffr[4][4];
#pragma unroll
    for (int g = 0; g < 4; ++g)
#pragma unroll
        for (int s = 0; s < 4; ++s)
            beffr[g][s] = g_beff[g * 256 + w * 64 + s * 16 + l15];
    float blinr[2];
#pragma unroll
    for (int s2 = 0; s2 < 2; ++s2) blinr[s2] = g_blin[w * 32 + s2 * 16 + l15];
    __syncthreads();

    // ================= AR t = 64..95 =================
    for (int t = 64; t <= 95; ++t) {
#pragma unroll
        for (int kt = 0; kt < 8; ++kt) {
            int off = (l15 * 512 + kt * 64 + lg * 16) ^ ((l15 & 7) << 4);
            ha[kt] = *(const short8_t*)((const char*)h_lds + off);
        }
        __syncthreads();

        if (t < 95) {
            float4_t ai[4], af[4];
            BINIT(ai, 0); BINIT(af, 1);
            GATEPASS(ai, 0); GATEPASS(af, 1);
            float4_t ag[4];
            BINIT(ag, 2);
            GATEPASS(ag, 2);
#pragma unroll
            for (int s = 0; s < 4; ++s)
#pragma unroll
                for (int r = 0; r < 4; ++r)
                    c_st[s][r] = sigm(af[s][r]) * c_st[s][r] + sigm(ai[s][r]) * tanh_fast(ag[s][r]);
            float4_t ao[4];
            BINIT(ao, 3);
            GATEPASS(ao, 3);
#pragma unroll
            for (int s = 0; s < 4; ++s)
#pragma unroll
                for (int r = 0; r < 4; ++r) {
                    float hv = sigm(ao[s][r]) * tanh_fast(c_st[s][r]);
                    int row = lg * 4 + r, col = w * 64 + s * 16 + l15;
                    int off = (row * 512 + col * 2) ^ ((row & 7) << 4);
                    *(unsigned short*)((char*)h_lds + off) = f2bf_rn(hv);
                }
        }

        // pred(t-1) = h(t-1) @ wlin^T + blin  (all 4 waves, 32 P-cols each)
        {
            float4_t pacc[2];
#pragma unroll
            for (int s2 = 0; s2 < 2; ++s2)
                pacc[s2] = (float4_t){blinr[s2], blinr[s2], blinr[s2], blinr[s2]};
#pragma unroll
            for (int kt = 0; kt < 8; ++kt)
#pragma unroll
                for (int s2 = 0; s2 < 2; ++s2) {
                    short8_t wl = *(const short8_t*)&g_Wlinp[((size_t)(w * 16 + s2 * 8 + kt)) * 512 + l * 8];
                    pacc[s2] = __builtin_amdgcn_mfma_f32_16x16x32_bf16(ha[kt], wl, pacc[s2], 0, 0, 0);
                }
            int ko = t - 64;
#pragma unroll
            for (int s2 = 0; s2 < 2; ++s2)
#pragma unroll
                for (int r = 0; r < 4; ++r)
                    out[(size_t)(blk * 16 + lg * 4 + r) * 4096 + ko * 128 + w * 32 + s2 * 16 + l15] = pacc[s2][r];
        }
        if (t < 95) __syncthreads();
    }
}

extern "C" void kernel_launch(void* const* d_in, const int* in_sizes, int n_in,
                              void* d_out, int out_size, void* d_ws, size_t ws_size,
                              hipStream_t stream) {
    const float* inp   = (const float*)d_in[0];
    const float* w_ih  = (const float*)d_in[1];
    const float* w_hh  = (const float*)d_in[2];
    const float* b_ih  = (const float*)d_in[3];
    const float* b_hh  = (const float*)d_in[4];
    const float* w_lin = (const float*)d_in[5];
    const float* b_lin = (const float*)d_in[6];
    (void)in_sizes; (void)n_in; (void)d_ws; (void)ws_size; (void)out_size;

    prep_kernel<<<256, 256, 0, stream>>>(w_ih, w_hh, b_ih, b_hh, w_lin, b_lin);
    prep2_kernel<<<1024, 256, 0, stream>>>(w_ih, w_hh, w_lin, b_ih, b_hh, b_lin);
    gx_kernel<<<1024, 256, 0, stream>>>(inp);
    lstm_persist<<<128, 256, 0, stream>>>((float*)d_out);
}

// Round 10
// 1005.838 us; speedup vs baseline: 1.8276x; 1.4199x over previous
//
#include <hip/hip_runtime.h>
#include <cstdint>
#include <cstddef>

typedef short short8_t __attribute__((ext_vector_type(8)));
typedef float float4_t __attribute__((ext_vector_type(4)));
typedef unsigned int uint4_t __attribute__((ext_vector_type(4)));

// ---- packed weights / intermediates (rebuilt every call) ----
__device__ __align__(16) unsigned short g_Whhp[4 * 128 * 512];  // [w][fw=(g*4+s)*8+kt][l*8+j]
__device__ __align__(16) unsigned short g_Weffp[4 * 128 * 512]; // same layout; Weff = Whh + Wih@wlin
__device__ __align__(16) unsigned short g_Wihp[4 * 64 * 512];   // [w][fw2=(g*4+s)*4+kt][..]
__device__ __align__(16) unsigned short g_Wlinp[4 * 16 * 512];  // [w][s2*8+kt][..]
__device__ float g_bias[1024];   // b_ih + b_hh (folded into Gx)
__device__ float g_beff[1024];   // bias + Wih @ b_lin (AR fold)
__device__ float g_blin[128];
// Gx = x @ Wih^T + bias, bf16, per (blk,t,w,lane) 128 B slabs in acc-init order
__device__ unsigned short g_Gx[134217728];   // 256 MB

__device__ __forceinline__ unsigned short f2bf_rn(float f) {
    union { float f; unsigned int u; } v; v.f = f;
    unsigned int u = v.u;
    return (unsigned short)((u + 0x7FFFu + ((u >> 16) & 1u)) >> 16);
}
__device__ __forceinline__ float sigm(float x) { return 1.0f / (1.0f + __expf(-x)); }
__device__ __forceinline__ float tanh_fast(float x) { return 2.0f / (1.0f + __expf(-2.0f * x)) - 1.0f; }
__device__ __forceinline__ float4_t sigm4(float4_t x) {
    float4_t r;
#pragma unroll
    for (int i = 0; i < 4; ++i) r[i] = sigm(x[i]);
    return r;
}
__device__ __forceinline__ float4_t tanh4(float4_t x) {
    float4_t r;
#pragma unroll
    for (int i = 0; i < 4; ++i) r[i] = tanh_fast(x[i]);
    return r;
}

__global__ void prep_kernel(const float* __restrict__ w_ih, const float* __restrict__ w_hh,
                            const float* __restrict__ b_ih, const float* __restrict__ b_hh,
                            const float* __restrict__ w_lin, const float* __restrict__ b_lin) {
    int idx = blockIdx.x * blockDim.x + threadIdx.x;
    int stride = gridDim.x * blockDim.x;
    for (int i = idx; i < 262144; i += stride) {           // Whh: n 0..1023, k 0..255
        int n = i >> 8, k = i & 255;
        int w = (n >> 6) & 3, g = n >> 8, s = (n >> 4) & 3, l15 = n & 15;
        int kt = k >> 5, lg = (k >> 3) & 3, j = k & 7;
        int fw = (g * 4 + s) * 8 + kt;
        g_Whhp[((size_t)(w * 128 + fw)) * 512 + (lg * 16 + l15) * 8 + j] = f2bf_rn(w_hh[n * 256 + k]);
    }
    for (int i = idx; i < 131072; i += stride) {           // Wih: n 0..1023, k 0..127
        int n = i >> 7, k = i & 127;
        int w = (n >> 6) & 3, g = n >> 8, s = (n >> 4) & 3, l15 = n & 15;
        int kt = k >> 5, lg = (k >> 3) & 3, j = k & 7;
        int fw2 = (g * 4 + s) * 4 + kt;
        g_Wihp[((size_t)(w * 64 + fw2)) * 512 + (lg * 16 + l15) * 8 + j] = f2bf_rn(w_ih[n * 128 + k]);
    }
    for (int i = idx; i < 32768; i += stride) {            // wlin: p 0..127, k 0..255
        int p = i >> 8, k = i & 255;
        int w = p >> 5, s2 = (p >> 4) & 1, l15 = p & 15;
        int kt = k >> 5, lg = (k >> 3) & 3, j = k & 7;
        g_Wlinp[((size_t)(w * 16 + s2 * 8 + kt)) * 512 + (lg * 16 + l15) * 8 + j] = f2bf_rn(w_lin[p * 256 + k]);
    }
    for (int i = idx; i < 1024; i += stride) g_bias[i] = b_ih[i] + b_hh[i];
    for (int i = idx; i < 128; i += stride) g_blin[i] = b_lin[i];
}

__global__ void prep2_kernel(const float* __restrict__ w_ih, const float* __restrict__ w_hh,
                             const float* __restrict__ w_lin, const float* __restrict__ b_ih,
                             const float* __restrict__ b_hh, const float* __restrict__ b_lin) {
    int i = blockIdx.x * 256 + threadIdx.x;                // grid 1024*256
    {
        int n = i >> 8, k = i & 255;
        float acc = w_hh[n * 256 + k];
#pragma unroll 4
        for (int p = 0; p < 128; ++p)
            acc += w_ih[n * 128 + p] * w_lin[p * 256 + k];
        int w = (n >> 6) & 3, g = n >> 8, s = (n >> 4) & 3, l15 = n & 15;
        int kt = k >> 5, lg = (k >> 3) & 3, j = k & 7;
        int fw = (g * 4 + s) * 8 + kt;
        g_Weffp[((size_t)(w * 128 + fw)) * 512 + (lg * 16 + l15) * 8 + j] = f2bf_rn(acc);
    }
    if (i < 1024) {
        float acc = b_ih[i] + b_hh[i];
        for (int p = 0; p < 128; ++p)
            acc += w_ih[i * 128 + p] * b_lin[p];
        g_beff[i] = acc;
    }
}

// ---- Gx: 2048 blocks (128 blk x 8 tchunk x 2 gate-pairs), 32 frags/wave -> no spill ----
__global__ void __launch_bounds__(256) gx_kernel(const float* __restrict__ inp) {
    const int b = blockIdx.x;
    const int blk = b >> 4, t0 = ((b >> 1) & 7) << 3, gp = b & 1;
    const int tid = threadIdx.x;
    const int w = tid >> 6, l = tid & 63, l15 = l & 15, lg = l >> 4;

    short8_t wih[32];
#pragma unroll
    for (int gi = 0; gi < 2; ++gi)
#pragma unroll
        for (int s = 0; s < 4; ++s)
#pragma unroll
            for (int kt = 0; kt < 4; ++kt)
                wih[(gi * 4 + s) * 4 + kt] =
                    *(const short8_t*)&g_Wihp[((size_t)(w * 64 + ((gp * 2 + gi) * 4 + s) * 4 + kt)) * 512 + l * 8];
    float biasr[2][4];
#pragma unroll
    for (int gi = 0; gi < 2; ++gi)
#pragma unroll
        for (int s = 0; s < 4; ++s)
            biasr[gi][s] = g_bias[(gp * 2 + gi) * 256 + w * 64 + s * 16 + l15];

    for (int tt = 0; tt < 8; ++tt) {
        int t = t0 + tt;
        const float* xp = inp + (size_t)(blk * 16 + l15) * 8192 + t * 128 + lg * 8;
        short8_t xa[4];
#pragma unroll
        for (int kt = 0; kt < 4; ++kt) {
            float4_t a = *(const float4_t*)(xp + kt * 32);
            float4_t b2 = *(const float4_t*)(xp + kt * 32 + 4);
            short8_t vv;
            vv[0] = (short)f2bf_rn(a[0]); vv[1] = (short)f2bf_rn(a[1]);
            vv[2] = (short)f2bf_rn(a[2]); vv[3] = (short)f2bf_rn(a[3]);
            vv[4] = (short)f2bf_rn(b2[0]); vv[5] = (short)f2bf_rn(b2[1]);
            vv[6] = (short)f2bf_rn(b2[2]); vv[7] = (short)f2bf_rn(b2[3]);
            xa[kt] = vv;
        }
        float4_t acc[2][4];
#pragma unroll
        for (int gi = 0; gi < 2; ++gi)
#pragma unroll
            for (int s = 0; s < 4; ++s) {
                float bb = biasr[gi][s];
                acc[gi][s] = (float4_t){bb, bb, bb, bb};
            }
#pragma unroll
        for (int kt = 0; kt < 4; ++kt)
#pragma unroll
            for (int gi = 0; gi < 2; ++gi)
#pragma unroll
                for (int s = 0; s < 4; ++s)
                    acc[gi][s] = __builtin_amdgcn_mfma_f32_16x16x32_bf16(xa[kt], wih[(gi * 4 + s) * 4 + kt], acc[gi][s], 0, 0, 0);

        uint4_t ov[4];
#pragma unroll
        for (int gi = 0; gi < 2; ++gi)
#pragma unroll
            for (int s = 0; s < 4; ++s) {
                unsigned d0 = ((unsigned)f2bf_rn(acc[gi][s][1]) << 16) | f2bf_rn(acc[gi][s][0]);
                unsigned d1 = ((unsigned)f2bf_rn(acc[gi][s][3]) << 16) | f2bf_rn(acc[gi][s][2]);
                int e = gi * 8 + s * 2;
                ov[e >> 2][e & 3] = d0;
                ov[(e + 1) >> 2][(e + 1) & 3] = d1;
            }
        char* dst = (char*)g_Gx + ((((size_t)blk * 64 + t) * 4 + w) * 64 + l) * 128 + gp * 64;
#pragma unroll
        for (int qq = 0; qq < 4; ++qq) *(uint4_t*)(dst + qq * 16) = ov[qq];
    }
}

// ==== named weight fragments: 60 AGPR + 32 VGPR + 36 LDS (literal indices only) ====
#define AG_LIST(X) \
 X(0,0,0) X(0,0,1) X(0,0,2) X(0,0,3) X(0,0,4) X(0,0,5) X(0,0,6) X(0,0,7) \
 X(0,1,0) X(0,1,1) X(0,1,2) X(0,1,3) X(0,1,4) X(0,1,5) X(0,1,6) X(0,1,7) \
 X(0,2,0) X(0,2,1) X(0,2,2) X(0,2,3) X(0,2,4) X(0,2,5) X(0,2,6) X(0,2,7) \
 X(0,3,0) X(0,3,1) X(0,3,2) X(0,3,3) X(0,3,4) X(0,3,5) X(0,3,6) X(0,3,7) \
 X(1,0,0) X(1,0,1) X(1,0,2) X(1,0,3) X(1,0,4) X(1,0,5) X(1,0,6) X(1,0,7) \
 X(1,1,0) X(1,1,1) X(1,1,2) X(1,1,3) X(1,1,4) X(1,1,5) X(1,1,6) X(1,1,7) \
 X(1,2,0) X(1,2,1) X(1,2,2) X(1,2,3) X(1,2,4) X(1,2,5) X(1,2,6) X(1,2,7) \
 X(1,3,0) X(1,3,1) X(1,3,2) X(1,3,3)
#define VR_LIST(X) \
 X(1,3,4) X(1,3,5) X(1,3,6) X(1,3,7) \
 X(2,0,0) X(2,0,1) X(2,0,2) X(2,0,3) X(2,0,4) X(2,0,5) X(2,0,6) X(2,0,7) \
 X(2,1,0) X(2,1,1) X(2,1,2) X(2,1,3) X(2,1,4) X(2,1,5) X(2,1,6) X(2,1,7) \
 X(2,2,0) X(2,2,1) X(2,2,2) X(2,2,3) X(2,2,4) X(2,2,5) X(2,2,6) X(2,2,7) \
 X(2,3,0) X(2,3,1) X(2,3,2) X(2,3,3)

#define DECLW(G,S,KT) short8_t q##G##S##KT;
#define LOADW(G,S,KT) q##G##S##KT = *(const short8_t*)&wsrc[(size_t)((((G)*4+(S))*8+(KT))) * 512 + l * 8];
#define PINW(G,S,KT)  asm volatile("" : "+a"(q##G##S##KT));

#define MM(S,KT,B) acc##S = __builtin_amdgcn_mfma_f32_16x16x32_bf16(ha[KT], B, acc##S, 0, 0, 0);
#define MQ(G,S,KT) MM(S,KT, q##G##S##KT)
#define MLD(S,KT,IDX) MM(S,KT, (*(const short8_t*)&lds_w[((size_t)w * 36 + (IDX)) * 512 + l * 8]))
#define MQ8(G,S) MQ(G,S,0) MQ(G,S,1) MQ(G,S,2) MQ(G,S,3) MQ(G,S,4) MQ(G,S,5) MQ(G,S,6) MQ(G,S,7)
#define ML8(S,B0) MLD(S,0,B0) MLD(S,1,(B0)+1) MLD(S,2,(B0)+2) MLD(S,3,(B0)+3) \
                  MLD(S,4,(B0)+4) MLD(S,5,(B0)+5) MLD(S,6,(B0)+6) MLD(S,7,(B0)+7)
#define GATE0() MQ8(0,0) MQ8(0,1) MQ8(0,2) MQ8(0,3)
#define GATE1() MQ8(1,0) MQ8(1,1) MQ8(1,2) MQ8(1,3)
#define GATE2() MQ8(2,0) MQ8(2,1) MQ8(2,2) MQ(2,3,0) MQ(2,3,1) MQ(2,3,2) MQ(2,3,3) \
                MLD(3,4,0) MLD(3,5,1) MLD(3,6,2) MLD(3,7,3)
#define GATE3() ML8(0,4) ML8(1,12) ML8(2,20) ML8(3,28)

#define U2F(u) __uint_as_float(u)
#define UNPK(D0,D1) (float4_t){U2F((unsigned)(D0) << 16), U2F((D0) & 0xFFFF0000u), \
                               U2F((unsigned)(D1) << 16), U2F((D1) & 0xFFFF0000u)}
#define GXI(G) { uint4_t q0_ = gxv[(G)*2], q1_ = gxv[(G)*2+1]; \
    acc0 = UNPK(q0_[0], q0_[1]); acc1 = UNPK(q0_[2], q0_[3]); \
    acc2 = UNPK(q1_[0], q1_[1]); acc3 = UNPK(q1_[2], q1_[3]); }
#define BIN(G) { acc0 = (float4_t){beffr[G][0],beffr[G][0],beffr[G][0],beffr[G][0]}; \
                 acc1 = (float4_t){beffr[G][1],beffr[G][1],beffr[G][1],beffr[G][1]}; \
                 acc2 = (float4_t){beffr[G][2],beffr[G][2],beffr[G][2],beffr[G][2]}; \
                 acc3 = (float4_t){beffr[G][3],beffr[G][3],beffr[G][3],beffr[G][3]}; }
#define HWRITE(S, ACCS, CS) { \
    _Pragma("unroll") \
    for (int r = 0; r < 4; ++r) { \
        float hv = sigm(ACCS[r]) * tanh_fast(CS[r]); \
        int row = lg * 4 + r, col = w * 64 + (S) * 16 + l15; \
        int off = (row * 512 + col * 2) ^ ((row & 7) << 4); \
        *(unsigned short*)((char*)h_lds + off) = f2bf_rn(hv); \
    } }
#define READHA() { \
    _Pragma("unroll") \
    for (int kt = 0; kt < 8; ++kt) { \
        int off = (l15 * 512 + kt * 64 + lg * 16) ^ ((l15 & 7) << 4); \
        ha[kt] = *(const short8_t*)((const char*)h_lds + off); \
    } }

// 128 blocks x 256 thr (1 wave/SIMD, 512 unified regs). Whh/Weff fully resident:
// 60 frags AGPR-pinned + 32 VGPR + 36 LDS per wave. h via 8KB LDS, 2 barriers/step.
__global__ void __launch_bounds__(256, 1) lstm_persist(float* __restrict__ out) {
    __shared__ __align__(16) unsigned short lds_w[4 * 36 * 512];   // 144 KB
    __shared__ __align__(16) unsigned short h_lds[16 * 256];       // 8 KB

    const int tid = threadIdx.x;
    const int w = tid >> 6, l = tid & 63, l15 = l & 15, lg = l >> 4;
    const int blk = blockIdx.x;

    AG_LIST(DECLW) VR_LIST(DECLW)

    const unsigned short* wsrc = g_Whhp + (size_t)w * 128 * 512;
    AG_LIST(LOADW) VR_LIST(LOADW)
    AG_LIST(PINW)

    for (int i = tid; i < 4 * 36 * 64; i += 256) {      // LDS frags = fw 92..127
        int fq = i >> 6, ch = i & 63;
        int wv = fq / 36, idx = fq % 36;
        *(uint4_t*)&lds_w[(size_t)fq * 512 + ch * 8] =
            *(const uint4_t*)&g_Whhp[((size_t)(wv * 128 + 92 + idx)) * 512 + ch * 8];
    }

    uint4_t gxv[8];
    {
        const char* gxb = (const char*)g_Gx + (((size_t)blk * 256 + w) * 64 + l) * 128;
#pragma unroll
        for (int qq = 0; qq < 8; ++qq) gxv[qq] = *(const uint4_t*)(gxb + qq * 16);
    }
    float4_t c0 = {0,0,0,0}, c1 = {0,0,0,0}, c2 = {0,0,0,0}, c3 = {0,0,0,0};
    float4_t tg0, tg1, tg2, tg3;
    short8_t ha[8];
    __syncthreads();

    // ================= encoder t = 0..63 =================
    for (int t = 0; t < 64; ++t) {
        if (t > 0) READHA();
        __syncthreads();

        float4_t acc0, acc1, acc2, acc3;
        GXI(2);                               // gate g
        if (t > 0) { GATE2(); }
        tg0 = tanh4(acc0); tg1 = tanh4(acc1); tg2 = tanh4(acc2); tg3 = tanh4(acc3);
        GXI(0);                               // gate i
        if (t > 0) { GATE0(); }
        tg0 = sigm4(acc0) * tg0; tg1 = sigm4(acc1) * tg1;
        tg2 = sigm4(acc2) * tg2; tg3 = sigm4(acc3) * tg3;
        GXI(1);                               // gate f
        if (t > 0) { GATE1(); }
        c0 = sigm4(acc0) * c0 + tg0; c1 = sigm4(acc1) * c1 + tg1;
        c2 = sigm4(acc2) * c2 + tg2; c3 = sigm4(acc3) * c3 + tg3;
        GXI(3);                               // gate o (last gxv use)
        if (t < 63) {                         // prefetch Gx(t+1) into freed gxv
            const char* gxb = (const char*)g_Gx + ((((size_t)blk * 64 + t + 1) * 4 + w) * 64 + l) * 128;
#pragma unroll
            for (int qq = 0; qq < 8; ++qq) gxv[qq] = *(const uint4_t*)(gxb + qq * 16);
        }
        if (t > 0) { GATE3(); }
        HWRITE(0, acc0, c0) HWRITE(1, acc1, c1) HWRITE(2, acc2, c2) HWRITE(3, acc3, c3)
        __syncthreads();
    }

    // ---- swap resident weights to Weff ----
    wsrc = g_Weffp + (size_t)w * 128 * 512;
    AG_LIST(LOADW) VR_LIST(LOADW)
    AG_LIST(PINW)
    for (int i = tid; i < 4 * 36 * 64; i += 256) {
        int fq = i >> 6, ch = i & 63;
        int wv = fq / 36, idx = fq % 36;
        *(uint4_t*)&lds_w[(size_t)fq * 512 + ch * 8] =
            *(const uint4_t*)&g_Weffp[((size_t)(wv * 128 + 92 + idx)) * 512 + ch * 8];
    }
    float beffr[4][4];
#pragma unroll
    for (int g = 0; g < 4; ++g)
#pragma unroll
        for (int s = 0; s < 4; ++s)
            beffr[g][s] = g_beff[g * 256 + w * 64 + s * 16 + l15];
    float blinr[2];
#pragma unroll
    for (int s2 = 0; s2 < 2; ++s2) blinr[s2] = g_blin[w * 32 + s2 * 16 + l15];
    __syncthreads();

    // ================= AR t = 64..95 =================
    for (int t = 64; t <= 95; ++t) {
        READHA();
        __syncthreads();

        if (t < 95) {
            float4_t acc0, acc1, acc2, acc3;
            BIN(2); GATE2();
            tg0 = tanh4(acc0); tg1 = tanh4(acc1); tg2 = tanh4(acc2); tg3 = tanh4(acc3);
            BIN(0); GATE0();
            tg0 = sigm4(acc0) * tg0; tg1 = sigm4(acc1) * tg1;
            tg2 = sigm4(acc2) * tg2; tg3 = sigm4(acc3) * tg3;
            BIN(1); GATE1();
            c0 = sigm4(acc0) * c0 + tg0; c1 = sigm4(acc1) * c1 + tg1;
            c2 = sigm4(acc2) * c2 + tg2; c3 = sigm4(acc3) * c3 + tg3;
            BIN(3); GATE3();
            HWRITE(0, acc0, c0) HWRITE(1, acc1, c1) HWRITE(2, acc2, c2) HWRITE(3, acc3, c3)
        }

        // pred(t-1) = h(t-1) @ wlin^T + blin (wlin JIT from L2; off critical path)
        {
            float4_t p0 = {blinr[0], blinr[0], blinr[0], blinr[0]};
            float4_t p1 = {blinr[1], blinr[1], blinr[1], blinr[1]};
#pragma unroll
            for (int kt = 0; kt < 8; ++kt) {
                short8_t wl0 = *(const short8_t*)&g_Wlinp[((size_t)(w * 16 + kt)) * 512 + l * 8];
                short8_t wl1 = *(const short8_t*)&g_Wlinp[((size_t)(w * 16 + 8 + kt)) * 512 + l * 8];
                p0 = __builtin_amdgcn_mfma_f32_16x16x32_bf16(ha[kt], wl0, p0, 0, 0, 0);
                p1 = __builtin_amdgcn_mfma_f32_16x16x32_bf16(ha[kt], wl1, p1, 0, 0, 0);
            }
            int ko = t - 64;
#pragma unroll
            for (int r = 0; r < 4; ++r) {
                out[(size_t)(blk * 16 + lg * 4 + r) * 4096 + ko * 128 + w * 32 + l15] = p0[r];
                out[(size_t)(blk * 16 + lg * 4 + r) * 4096 + ko * 128 + w * 32 + 16 + l15] = p1[r];
            }
        }
        if (t < 95) __syncthreads();
    }
}

extern "C" void kernel_launch(void* const* d_in, const int* in_sizes, int n_in,
                              void* d_out, int out_size, void* d_ws, size_t ws_size,
                              hipStream_t stream) {
    const float* inp   = (const float*)d_in[0];
    const float* w_ih  = (const float*)d_in[1];
    const float* w_hh  = (const float*)d_in[2];
    const float* b_ih  = (const float*)d_in[3];
    const float* b_hh  = (const float*)d_in[4];
    const float* w_lin = (const float*)d_in[5];
    const float* b_lin = (const float*)d_in[6];
    (void)in_sizes; (void)n_in; (void)d_ws; (void)ws_size; (void)out_size;

    prep_kernel<<<256, 256, 0, stream>>>(w_ih, w_hh, b_ih, b_hh, w_lin, b_lin);
    prep2_kernel<<<1024, 256, 0, stream>>>(w_ih, w_hh, w_lin, b_ih, b_hh, b_lin);
    gx_kernel<<<2048, 256, 0, stream>>>(inp);
    lstm_persist<<<128, 256, 0, stream>>>((float*)d_out);
}